// Round 13
// baseline (127.721 us; speedup 1.0000x reference)
//
#include <hip/hip_runtime.h>
#include <hip/hip_bf16.h>
#include <math.h>

// Problem constants
#define K_  32
#define HN  16      // n/2
#define N_  32
#define M_  128
#define B_  8
#define T_  2048
#define D_  128
#define BT  (B_*T_)     // 16384
#define KA  1056        // GEMM K: 1024 interleaved (Re,Im) + 32 xp
#define CHK 32          // chunks per series
#define CL  64          // chunk length (T/CHK)

typedef short short8 __attribute__((ext_vector_type(8)));
typedef float floatx4 __attribute__((ext_vector_type(4)));
typedef unsigned short ushort_t;
typedef unsigned int uint_t;

__device__ __forceinline__ ushort_t f2bf(float f) {
    __hip_bfloat16 h = __float2bfloat16(f);
    return *reinterpret_cast<ushort_t*>(&h);
}
__device__ __forceinline__ uint_t pack_bf2(float re, float im) {
    return ((uint_t)f2bf(im) << 16) | (uint_t)f2bf(re);
}

// ---------------------------------------------------------------------------
// K_PRE: fused independent preprocessing, partitioned by blockIdx (R11/R12).
//   block 0        : lambda/Bp table
//   blocks 1..272  : Wt build (bf16, transposed, interleaved Re/Im)
//   blocks 273..784: xp projection -> xpT (shifted, time-major) + A2 cols
// ---------------------------------------------------------------------------
__global__ __launch_bounds__(256) void k_pre(const float* __restrict__ theta,
                                             const float* __restrict__ lnC_r,
                                             const float* __restrict__ lnC_i,
                                             const float* __restrict__ D,
                                             const float* __restrict__ x,
                                             const float* __restrict__ R,
                                             float* __restrict__ ws,
                                             ushort_t* __restrict__ Wt,
                                             float* __restrict__ xpT,
                                             ushort_t* __restrict__ A2) {
    __shared__ float xls[32 * 128];
    int bid = blockIdx.x, tid = threadIdx.x;
    if (bid == 0) {
        #pragma unroll
        for (int rep = 0; rep < 2; ++rep) {
            int t2 = rep * 256 + tid;          // k*16 + j
            int k = t2 >> 4, j = t2 & 15;
            float angj = theta[k * HN + j];
            float pr = 1.f, pi = 0.f;
            for (int i = 0; i < N_; ++i) {
                if (i == j) continue;
                float angi = (i < HN) ? theta[k * HN + i] : -theta[k * HN + i - HN];
                float d = angi - angj;
                float tr = 1.f - cosf(d);
                float ti = -sinf(d);
                float nr = pr * tr - pi * ti;
                float ni = pr * ti + pi * tr;
                pr = nr; pi = ni;
            }
            float den = pr * pr + pi * pi;
            ws[t2]        = cosf(angj);
            ws[512 + t2]  = sinf(angj);
            ws[1024 + t2] = pr / den;
            ws[1536 + t2] = -pi / den;
        }
    } else if (bid <= 272) {
        int t = (bid - 1) * 256 + tid;
        const float inv = 1.f / 32.f;
        if (t < K_ * HN * M_) {                 // 65536
            int m = t & 127, j = (t >> 7) & 15, k = t >> 11;
            int i0 = (k * N_ + j) * M_ + m;
            int i1 = (k * N_ + j + HN) * M_ + m;
            float r0 = expf(lnC_r[i0]), c0 = cosf(lnC_i[i0]), s0 = sinf(lnC_i[i0]);
            float r1 = expf(lnC_r[i1]), c1 = cosf(lnC_i[i1]), s1 = sinf(lnC_i[i1]);
            float wr = (r0 * c0 + r1 * c1) * inv;
            float wi = (r1 * s1 - r0 * s0) * inv;
            *(uint_t*)(Wt + (size_t)m * KA + k * 32 + 2 * j) = pack_bf2(wr, wi);
        } else if (t < K_ * HN * M_ + K_ * M_) {
            int u = t - K_ * HN * M_;
            int m = u & 127, k = u >> 7;
            Wt[(size_t)m * KA + 1024 + k] = f2bf(D[k * M_ + m] * inv);
        }
    } else {
        int xb = bid - 273;                     // 0..511
        int b = xb >> 6;
        int tbase = (xb & 63) * 32;
        const float4* xsrc = (const float4*)(x + ((size_t)b * T_ + tbase) * D_);
        float4* xd = (float4*)xls;
        #pragma unroll
        for (int e = 0; e < 4; ++e) xd[tid + 256 * e] = xsrc[tid + 256 * e];
        __syncthreads();
        int kk = tid & 31, rg = tid >> 5;       // rg 0..7
        float accv[4] = {0.f, 0.f, 0.f, 0.f};
        #pragma unroll 4
        for (int i = 0; i < D_; ++i) {
            float rv = R[i * K_ + kk];
            #pragma unroll
            for (int rr = 0; rr < 4; ++rr)
                accv[rr] += xls[(rg + 8 * rr) * D_ + i] * rv;
        }
        #pragma unroll
        for (int rr = 0; rr < 4; ++rr) {
            int tt = tbase + rg + 8 * rr;
            A2[(size_t)(tt * 8 + b) * KA + 1024 + kk] = f2bf(accv[rr]);
            size_t base = (size_t)(b * K_ + kk) * T_;
            if (tt < T_ - 1) xpT[base + tt + 1] = accv[rr];
            if (tt == 0)     xpT[base] = 0.f;
        }
    }
}

// ---------------------------------------------------------------------------
// K_SCAN: fused scan_ends + carries + scan_write for one (b,k) series (R12).
// ---------------------------------------------------------------------------
__global__ __launch_bounds__(512) void k_scan(const float* __restrict__ xpT,
                                              const float* __restrict__ ws,
                                              uint_t* __restrict__ A2u) {
    __shared__ float xls[T_];          // 8 KB
    __shared__ float Er[512], Ei[512]; // 4 KB

    int tid = threadIdx.x;
    int k = blockIdx.x & 31, b = blockIdx.x >> 5;
    int c = tid >> 4, j = tid & 15;
    int col = k * 16 + j;

    ((float4*)xls)[tid] = ((const float4*)(xpT + (size_t)(b * K_ + k) * T_))[tid];
    __syncthreads();

    float lr = ws[col], li = ws[512 + col];
    float br = ws[1024 + col], bi = ws[1536 + col];

    {
        float sr = 0.f, si = 0.f;
        const float* xc = xls + c * CL;
        #pragma unroll 4
        for (int p = 0; p < CL; ++p) {
            float x1 = xc[p];
            float nr = br * x1 + lr * sr - li * si;
            float ni = bi * x1 + lr * si + li * sr;
            sr = nr; si = ni;
        }
        Er[c * 16 + j] = sr;
        Ei[c * 16 + j] = si;
    }
    __syncthreads();

    if (tid < 16) {
        float pr = lr, pi = li;            // lambda^64 via 6 squarings
        #pragma unroll
        for (int q = 0; q < 6; ++q) {
            float nr = pr * pr - pi * pi;
            float ni = 2.f * pr * pi;
            pr = nr; pi = ni;
        }
        float sr = 0.f, si = 0.f;
        for (int cc = 0; cc < CHK; ++cc) {
            int idx = cc * 16 + tid;
            float er = Er[idx], ei = Ei[idx];
            Er[idx] = sr; Ei[idx] = si;
            float nr = pr * sr - pi * si + er;
            float ni = pr * si + pi * sr + ei;
            sr = nr; si = ni;
        }
    }
    __syncthreads();

    {
        float sr = Er[c * 16 + j], si = Ei[c * 16 + j];
        int t0 = c * CL;
        const float* xc = xls + t0;
        uint_t* Ab = A2u + (size_t)(t0 * 8 + b) * (KA / 2) + col;
        #pragma unroll 4
        for (int p = 0; p < CL; ++p) {
            float x1 = xc[p];
            float nr = br * x1 + lr * sr - li * si;
            float ni = bi * x1 + lr * si + li * sr;
            sr = nr; si = ni;
            Ab[0] = pack_bf2(sr, si);
            Ab += 8 * (KA / 2);
        }
    }
}

// ---------------------------------------------------------------------------
// K5: bf16 MFMA GEMM, 64-row blocks. 256 blocks x 256 thr; block = 64 rows x
// 128 cols. Wave: rh = wave&1 (rows rh*32..+31, two 16-row groups), chh =
// wave>>1 (cols chh*64..+63). 8 accs; per K-group 6 A + 12 B loads -> 24
// MFMAs (ratio 1.33 vs R12's 0.8); B L2 traffic halved to 69 MB.
// K-accumulation order per acc identical to R12 -> bit-identical output.
// ---------------------------------------------------------------------------
__global__ __launch_bounds__(256, 2) void k_gemm(const ushort_t* __restrict__ A2,
                                                 const ushort_t* __restrict__ Wt,
                                                 const float* __restrict__ Do,
                                                 float* __restrict__ out) {
    int tid = threadIdx.x;
    int wave = tid >> 6;
    int rh = wave & 1;
    int chh = wave >> 1;
    int lane = tid & 63;
    int l16 = lane & 15;
    int quad = lane >> 4;
    int row0 = blockIdx.x * 64 + rh * 32;

    const ushort_t* Ap0 = A2 + (size_t)(row0 + l16) * KA + quad * 8;
    const ushort_t* Ap1 = Ap0 + (size_t)16 * KA;
    const ushort_t* Wp  = Wt + (size_t)(chh * 64 + l16) * KA + quad * 8;

    floatx4 acc[2][4];
    #pragma unroll
    for (int rg = 0; rg < 2; ++rg)
        #pragma unroll
        for (int n = 0; n < 4; ++n) acc[rg][n] = (floatx4){0.f, 0.f, 0.f, 0.f};

    for (int g = 0; g < 11; ++g) {
        int k0 = g * 96;
        short8 a[2][3];
        #pragma unroll
        for (int s = 0; s < 3; ++s) {
            a[0][s] = *(const short8*)(Ap0 + k0 + s * 32);
            a[1][s] = *(const short8*)(Ap1 + k0 + s * 32);
        }
        short8 bv[4][3];
        #pragma unroll
        for (int n = 0; n < 4; ++n) {
            #pragma unroll
            for (int s = 0; s < 3; ++s)
                bv[n][s] = *(const short8*)(Wp + (size_t)n * 16 * KA + k0 + s * 32);
        }
        #pragma unroll
        for (int s = 0; s < 3; ++s)
            #pragma unroll
            for (int rg = 0; rg < 2; ++rg)
                #pragma unroll
                for (int n = 0; n < 4; ++n)
                    acc[rg][n] = __builtin_amdgcn_mfma_f32_16x16x32_bf16(
                        a[rg][s], bv[n][s], acc[rg][n], 0, 0, 0);
    }

    #pragma unroll
    for (int rg = 0; rg < 2; ++rg) {
        #pragma unroll
        for (int n = 0; n < 4; ++n) {
            int col = chh * 64 + n * 16 + l16;
            float dov = Do[col];
            #pragma unroll
            for (int q = 0; q < 4; ++q) {
                int r = row0 + rg * 16 + quad * 4 + q;
                int b = r & 7, t = r >> 3;
                out[(size_t)(b * T_ + t) * M_ + col] = acc[rg][n][q] + dov;
            }
        }
    }
}

// ---------------------------------------------------------------------------
extern "C" void kernel_launch(void* const* d_in, const int* in_sizes, int n_in,
                              void* d_out, int out_size, void* d_ws, size_t ws_size,
                              hipStream_t stream) {
    const float* x     = (const float*)d_in[0];
    const float* R     = (const float*)d_in[1];
    const float* theta = (const float*)d_in[2];
    const float* lnC_r = (const float*)d_in[3];
    const float* lnC_i = (const float*)d_in[4];
    const float* D     = (const float*)d_in[5];
    const float* Do    = (const float*)d_in[6];
    float* out = (float*)d_out;

    float* wsf   = (float*)d_ws;
    float* lambp = wsf;                               // 2048 floats
    ushort_t* Wt = (ushort_t*)(wsf + 2048);           // 135168 ushorts
    ushort_t* A2 = (ushort_t*)(wsf + 2048 + 67584);   // BT*KA ushorts
    float* xpT   = wsf + 2048 + 67584 + 8650752;      // 524288 floats

    k_pre<<<785, 256, 0, stream>>>(theta, lnC_r, lnC_i, D, x, R,
                                   lambp, Wt, xpT, A2);
    k_scan<<<256, 512, 0, stream>>>(xpT, lambp, (uint_t*)A2);
    k_gemm<<<256, 256, 0, stream>>>(A2, Wt, Do, out);
}